// Round 6
// baseline (3820.498 us; speedup 1.0000x reference)
//
#include <hip/hip_runtime.h>
#include <math.h>

// Problem constants
#define B_   256
#define T_   100
#define IN_  132
#define OUT_ 132
#define H_   1024
#define BH   ((size_t)B_ * H_)

typedef _Float16 f16;
typedef _Float16 f16x8 __attribute__((ext_vector_type(8)));
typedef float    f32x4 __attribute__((ext_vector_type(4)));

#define MFMA16(a, b, c) __builtin_amdgcn_mfma_f32_16x16x32_f16((a), (b), (c), 0, 0, 0)

#define AS1 __attribute__((address_space(1)))
#define AS3 __attribute__((address_space(3)))

__device__ __forceinline__ void gl_lds16(const void* g, void* l) {
    __builtin_amdgcn_global_load_lds((AS1 void*)g, (AS3 void*)l, 16, 0, 0);
}

__device__ __forceinline__ float sigmoidf_(float x) {
    return 1.0f / (1.0f + __expf(-x));
}
__device__ __forceinline__ float tanhf_(float x) {
    float e = __expf(2.0f * x);
    return 1.0f - 2.0f / (e + 1.0f);
}

// ---------------- prep kernels ----------------

__global__ void conv_pad(const float* __restrict__ src, f16* __restrict__ dst,
                         int src_rows, int src_k, int dst_k) {
    int k = blockIdx.x * 256 + threadIdx.x;
    int r = blockIdx.y;
    if (k >= dst_k) return;
    float v = (r < src_rows && k < src_k) ? src[(size_t)r * src_k + k] : 0.0f;
    dst[(size_t)r * dst_k + k] = (f16)v;
}

// WdT[m][k] = Wd[k][m], padded to k<160. grid (1, 1024), block 256
__global__ void convT_kernel(const float* __restrict__ Wd, f16* __restrict__ WdT) {
    int k = blockIdx.x * 256 + threadIdx.x;
    int m = blockIdx.y;
    if (k >= 160) return;
    float v = (k < IN_) ? Wd[(size_t)k * H_ + m] : 0.0f;
    WdT[(size_t)m * 160 + k] = (f16)v;
}

__global__ void bias_add_kernel(const float* __restrict__ a, const float* __restrict__ b,
                                float* __restrict__ dst, int n) {
    int i = blockIdx.x * 256 + threadIdx.x;
    if (i < n) dst[i] = a[i] + b[i];
}

// bfb[j] = sum_k Wih1[j][k] * bd[k]
__global__ void bfb_kernel(const float* __restrict__ Wih1, const float* __restrict__ bd,
                           float* __restrict__ bfb) {
    int j = blockIdx.x * 256 + threadIdx.x;
    if (j >= 4096) return;
    float s = 0.0f;
    for (int k = 0; k < IN_; ++k) s += Wih1[(size_t)j * IN_ + k] * bd[k];
    bfb[j] = s;
}

__global__ void zero_kernel(float* __restrict__ p, int n) {
    int i = blockIdx.x * blockDim.x + threadIdx.x;
    int st = gridDim.x * blockDim.x;
    for (; i < n; i += st) p[i] = 0.0f;
}

// Pack fp32 [4096][1024] weight into direct-fragment layout:
// Wpk[wsel][jt(64)][kk(32)][c(64)][64B], col c: gate=(c>>4)&3, jj=c&15,
// src row = gate*1024 + jt*16 + jj, k = kk*32 + ch*8 + e (plain order).
// grid (64 jt, 32 kk), block 256 (one thread = one 16B sub-chunk).
__global__ __launch_bounds__(256) void pack_w(const float* __restrict__ W,
                                              f16* __restrict__ Wpk, int wsel) {
    int jt = blockIdx.x, kk = blockIdx.y;
    f16* dst = Wpk + (((size_t)wsel * 64 + jt) * 32 + kk) * 2048;
    int u = threadIdx.x;
    int c = u >> 2, ch = u & 3;
    int row = ((c >> 4) & 3) * 1024 + jt * 16 + (c & 15);
    const float* s = W + (size_t)row * 1024 + kk * 32 + ch * 8;
    f16x8 v;
#pragma unroll
    for (int e = 0; e < 8; ++e) v[e] = (f16)s[e];
    *(f16x8*)(dst + (size_t)c * 32 + ch * 8) = v;
}

// Same but f16 source (for Wfb [4096][1024]).
__global__ __launch_bounds__(256) void pack_wf16(const f16* __restrict__ W,
                                                 f16* __restrict__ Wpk, int wsel) {
    int jt = blockIdx.x, kk = blockIdx.y;
    f16* dst = Wpk + (((size_t)wsel * 64 + jt) * 32 + kk) * 2048;
    int u = threadIdx.x;
    int c = u >> 2, ch = u & 3;
    int row = ((c >> 4) & 3) * 1024 + jt * 16 + (c & 15);
    f16x8 v = *(const f16x8*)(W + (size_t)row * 1024 + kk * 32 + ch * 8);
    *(f16x8*)(dst + (size_t)c * 32 + ch * 8) = v;
}

// Pack Wih1 fp32 [4096][132] -> W0pk[jt(64)][kk(5)][2048], k padded to 160.
// grid (64 jt, 5 kk), block 256.
__global__ __launch_bounds__(256) void pack_w0(const float* __restrict__ W,
                                               f16* __restrict__ W0pk) {
    int jt = blockIdx.x, kk = blockIdx.y;
    f16* dst = W0pk + ((size_t)jt * 5 + kk) * 2048;
    int u = threadIdx.x;
    int c = u >> 2, ch = u & 3;
    int row = ((c >> 4) & 3) * 1024 + jt * 16 + (c & 15);
    f16x8 v;
#pragma unroll
    for (int e = 0; e < 8; ++e) {
        int k = kk * 32 + ch * 8 + e;
        v[e] = (f16)((k < IN_) ? W[(size_t)row * IN_ + k] : 0.0f);
    }
    *(f16x8*)(dst + (size_t)c * 32 + ch * 8) = v;
}

// Pack seq fp32 [B][T][IN] -> seqpk[t][kk(5)][256 b][32] f16. grid (5, 100), block 256.
__global__ __launch_bounds__(256) void pack_seq(const float* __restrict__ seq,
                                                f16* __restrict__ seqpk) {
    int kt = blockIdx.x, t = blockIdx.y;
    int b = threadIdx.x;
    f16* d = seqpk + (((size_t)t * 5 + kt) * 256 + b) * 32;
#pragma unroll
    for (int ch = 0; ch < 4; ++ch) {
        f16x8 v;
#pragma unroll
        for (int e = 0; e < 8; ++e) {
            int k = kt * 32 + ch * 8 + e;
            v[e] = (f16)((k < IN_) ? seq[((size_t)b * T_ + t) * IN_ + k] : 0.0f);
        }
        *(f16x8*)(d + ch * 8) = v;
    }
}

// Wfb = W0(fp16,[4096][160]) @ WdT(fp16,[1024][160])^T -> [4096][1024] fp16
// grid (32 m-tiles, 8 n-tiles), block 256 (4 waves 2x2 of 64x64). One-time prep.
__global__ __launch_bounds__(256) void wfb_mfma(
    const f16* __restrict__ W0, const f16* __restrict__ WdT, f16* __restrict__ Wfb)
{
    const int m0 = blockIdx.x * 128;
    const int n0 = blockIdx.y * 128;
    const int tid  = threadIdx.x;
    const int lane = tid & 63;
    const int w    = tid >> 6;
    const int lx   = lane & 15;
    const int quad = lane >> 4;
    const int wrow = w >> 1, wcol = w & 1;

    __shared__ __align__(16) char lds[32768];   // 2 x (A 8KB + B 8KB)

    auto stA = [&](int kt, int buf) {
        char* base = lds + buf * 16384;
#pragma unroll
        for (int i = 0; i < 2; ++i) {
            int r  = w * 32 + i * 16 + (lane >> 2);
            int sg = (lane & 3) ^ (r & 3);
            const f16* g = W0 + (size_t)(m0 + r) * 160 + kt * 32 + sg * 8;
            gl_lds16(g, base + (size_t)(w * 32 + i * 16) * 64);
        }
    };
    auto stB = [&](int kt, int buf) {
        char* base = lds + 8192 + buf * 16384;
#pragma unroll
        for (int i = 0; i < 2; ++i) {
            int r  = w * 32 + i * 16 + (lane >> 2);
            int sg = (lane & 3) ^ (r & 3);
            const f16* g = WdT + (size_t)(n0 + r) * 160 + kt * 32 + sg * 8;
            gl_lds16(g, base + (size_t)(w * 32 + i * 16) * 64);
        }
    };

    f32x4 acc[4][4];
#pragma unroll
    for (int m = 0; m < 4; ++m)
#pragma unroll
        for (int n = 0; n < 4; ++n) acc[m][n] = (f32x4){0.f, 0.f, 0.f, 0.f};

    stA(0, 0); stB(0, 0);
    for (int kt = 0; kt < 5; ++kt) {
        __syncthreads();
        if (kt + 1 < 5) { stA(kt + 1, (kt + 1) & 1); stB(kt + 1, (kt + 1) & 1); }
        const char* bA = lds + (kt & 1) * 16384;
        const char* bB = lds + 8192 + (kt & 1) * 16384;
        f16x8 af[4], bf[4];
#pragma unroll
        for (int m = 0; m < 4; ++m) {
            int R = wrow * 64 + m * 16 + lx;
            af[m] = *(const f16x8*)(bA + R * 64 + ((quad ^ (R & 3)) * 16));
        }
#pragma unroll
        for (int n = 0; n < 4; ++n) {
            int R = wcol * 64 + n * 16 + lx;
            bf[n] = *(const f16x8*)(bB + R * 64 + ((quad ^ (R & 3)) * 16));
        }
#pragma unroll
        for (int m = 0; m < 4; ++m)
#pragma unroll
            for (int n = 0; n < 4; ++n)
                acc[m][n] = MFMA16(af[m], bf[n], acc[m][n]);
    }

#pragma unroll
    for (int m = 0; m < 4; ++m)
#pragma unroll
        for (int n = 0; n < 4; ++n)
#pragma unroll
            for (int r = 0; r < 4; ++r) {
                int row = m0 + wrow * 64 + m * 16 + quad * 4 + r;
                int col = n0 + wcol * 64 + n * 16 + lx;
                Wfb[(size_t)row * H_ + col] = (f16)acc[m][n][r];
            }
}

// ---------------- fused per-step kernel (direct-VGPR, high-TLP) ----------------
// grid (64 jt(16 j), 8 mb(32 batch), 3 cells), block 128 = 2 waves.
// Wave tile 32 batch x 64 cols (16 j x 4 gates; col c = n*16+lx -> gate=n,
// j=jt*16+lx -> lane-local LSTM update). The 2 waves SPLIT K (wave0 [0,nh),
// wave1 [nh,ntot)) and combine via one 8KB LDS exchange. 3072 waves total =
// 12 waves/CU (the TLP that hides LLC latency). Every fragment load is a
// contiguous coalesced 1KB per wave straight to VGPR; 2-deep register
// prefetch; __launch_bounds__(128,4) pins VGPR<=128 for the 16-waves/CU bucket.
__global__ __launch_bounds__(128, 4) void step_mfma(
    const f16* __restrict__ seqpk,    // [T][5][256][32]
    const f16* __restrict__ h2pkP,    // [32][256][32] prev h2 packed (zeros at t=0)
    const f16* __restrict__ h01pkC,   // [2][32][256][32] old h0,h1 packed
    f16* __restrict__ h01pkN,         // [2][32][256][32] new h0,h1 packed
    f16* __restrict__ h2pkN,          // [32][256][32] new h2 packed
    f16* __restrict__ histN,          // [256][1024] linear h2 for decode (hist + t*BH)
    float* __restrict__ c_st,         // [3][B][H]
    const f16* __restrict__ W0pk,     // [64][5][2048]
    const f16* __restrict__ Wpk,      // [6][64][32][2048]
    const float* __restrict__ bias_comb,  // [3][4096]
    const float* __restrict__ bfb,        // [4096]
    const int* __restrict__ cnum, const int* __restrict__ gnum,
    int t)
{
    const int jt   = blockIdx.x;
    const int mb   = blockIdx.y;       // 8 tiles of 32 batch rows
    const int l    = blockIdx.z;
    const int tid  = threadIdx.x;
    const int lane = tid & 63;
    const int w    = tid >> 6;         // 0/1 : K-split half
    const int lx   = lane & 15;
    const int quad = lane >> 4;

    __shared__ float ex[2][4][4][64];  // 8 KB: partial for dst-wave's own rows

    // ---- operand decode (byte pointers; per-kk strides: A 16KB, B 4KB)
    bool use_gt = false;
    int n0 = 32;
    const char *A0 = nullptr, *B0 = nullptr;
    const char* wbase = (const char*)Wpk + (size_t)jt * 131072;   // + wsel*8MB
    if (l == 0) {
        int cn = cnum[0], gn = gnum[0];
        use_gt = (t % (cn + gn)) < gn;
        if (use_gt)      { A0 = (const char*)(seqpk + (size_t)t * 40960);
                           B0 = (const char*)(W0pk + (size_t)jt * 10240); n0 = 5; }
        else if (t == 0) { n0 = 0; }
        else             { A0 = (const char*)h2pkP; B0 = wbase + (size_t)5 * 8388608; }
    } else if (l == 1) { A0 = (const char*)h01pkC;        B0 = wbase + (size_t)1 * 8388608; }
    else               { A0 = (const char*)(h01pkC + BH); B0 = wbase + (size_t)3 * 8388608; }
    const char* A1 = (l == 0) ? (const char*)h01pkC
                   : (l == 1) ? (const char*)(h01pkC + BH) : (const char*)h2pkP;
    const char* B1 = wbase + (size_t)((l == 0) ? 0 : (l == 1) ? 2 : 4) * 8388608;
    const int ntot = n0 + 32;
    const int nh = (ntot + 1) >> 1;
    const int lo = w ? nh : 0;
    const int hi = w ? ntot : nh;

    const int aoff = (mb * 32 + lx) * 64 + quad * 16;
    const int boff = lx * 64 + quad * 16;

    f32x4 acc[2][4];
#pragma unroll
    for (int m = 0; m < 2; ++m)
#pragma unroll
        for (int n = 0; n < 4; ++n) acc[m][n] = (f32x4){0.f, 0.f, 0.f, 0.f};

    // ---- 2 statically-named prefetch stages
    f16x8 a0[2], b0[4], a1s[2], b1s[4];

    auto LD = [&](f16x8 (&aa)[2], f16x8 (&bb)[4], int itx) {
        int kk; const char *pa, *pb;
        if (itx < n0) { kk = itx;      pa = A0; pb = B0; }
        else          { kk = itx - n0; pa = A1; pb = B1; }
        pa += (size_t)kk * 16384 + aoff;
        pb += (size_t)kk * 4096 + boff;
#pragma unroll
        for (int m = 0; m < 2; ++m) aa[m] = *(const f16x8*)(pa + m * 1024);
#pragma unroll
        for (int n = 0; n < 4; ++n) bb[n] = *(const f16x8*)(pb + n * 1024);
    };
    auto MF = [&](f16x8 (&aa)[2], f16x8 (&bb)[4]) {
        __builtin_amdgcn_s_setprio(1);
#pragma unroll
        for (int m = 0; m < 2; ++m)
#pragma unroll
            for (int n = 0; n < 4; ++n)
                acc[m][n] = MFMA16(aa[m], bb[n], acc[m][n]);
        __builtin_amdgcn_s_setprio(0);
    };

    const int n = hi - lo;
    if (n > 0) LD(a0,  b0,  lo);
    if (n > 1) LD(a1s, b1s, lo + 1);

    int done = 0;
    while (done + 2 <= n) {
        MF(a0, b0);
        if (done + 2 < n) LD(a0, b0, lo + done + 2);
        MF(a1s, b1s);
        if (done + 3 < n) LD(a1s, b1s, lo + done + 3);
        done += 2;
    }
    if (done < n) MF(a0, b0);          // odd remainder

    // ---- K-combine: each wave publishes the OTHER wave's rows (m = 1-w)
    if (w == 0) {
#pragma unroll
        for (int nn = 0; nn < 4; ++nn)
#pragma unroll
            for (int r = 0; r < 4; ++r) ex[1][nn][r][lane] = acc[1][nn][r];
    } else {
#pragma unroll
        for (int nn = 0; nn < 4; ++nn)
#pragma unroll
            for (int r = 0; r < 4; ++r) ex[0][nn][r][lane] = acc[0][nn][r];
    }
    __syncthreads();

    f32x4 fa[4];
    if (w == 0) {
#pragma unroll
        for (int nn = 0; nn < 4; ++nn) fa[nn] = acc[0][nn];
    } else {
#pragma unroll
        for (int nn = 0; nn < 4; ++nn) fa[nn] = acc[1][nn];
    }

    // ---- lane-local LSTM epilogue (wave w owns rows mb*32 + w*16 .. +15)
    const int j = jt * 16 + lx;
    const float* bc = bias_comb + l * 4096;
    const bool addfb = (l == 0 && !use_gt && t > 0);
    float bi  = bc[j]        + (addfb ? bfb[j]        : 0.f);
    float bff = bc[1024 + j] + (addfb ? bfb[1024 + j] : 0.f);
    float bg  = bc[2048 + j] + (addfb ? bfb[2048 + j] : 0.f);
    float bo  = bc[3072 + j] + (addfb ? bfb[3072 + j] : 0.f);
#pragma unroll
    for (int r = 0; r < 4; ++r) {
        int b = mb * 32 + w * 16 + quad * 4 + r;
        float gi = fa[0][r] + ex[w][0][r][lane] + bi;
        float gf = fa[1][r] + ex[w][1][r][lane] + bff;
        float gg = fa[2][r] + ex[w][2][r][lane] + bg;
        float go = fa[3][r] + ex[w][3][r][lane] + bo;
        size_t ix = ((size_t)l * B_ + b) * H_ + j;
        float cn = sigmoidf_(gf) * c_st[ix] + sigmoidf_(gi) * tanhf_(gg);
        c_st[ix] = cn;
        float hv = sigmoidf_(go) * tanhf_(cn);
        f16 hv16 = (f16)hv;
        size_t pix = ((size_t)(j >> 5) * 256 + b) * 32 + (j & 31);   // packed
        if (l == 2) { h2pkN[pix] = hv16; histN[(size_t)b * H_ + j] = hv16; }
        else        h01pkN[(size_t)l * BH + pix] = hv16;
    }
}

// ---------------- final batched decoder ----------------
// out[b][t][n] = hist[t][b][:] @ Wd^T + bd. M=25600 rows (t*256+b), N=160(132), K=1024.
// grid (200, 5), block 256 (4 waves stacked on M; tile 128x32).
__global__ __launch_bounds__(256) void decode_mfma(
    const f16* __restrict__ hist,   // [100][256][1024]
    const f16* __restrict__ Wd16,   // [160][1024]
    const float* __restrict__ bd,   // [132]
    float* __restrict__ dout)       // [256][T*132]
{
    const int r0  = blockIdx.x * 128;
    const int nb0 = blockIdx.y * 32;
    const int tid  = threadIdx.x;
    const int lane = tid & 63;
    const int w    = tid >> 6;
    const int lx   = lane & 15;
    const int quad = lane >> 4;

    __shared__ __align__(16) char lds[20480];   // 2 x (A 8KB + B 2KB)

    auto stA = [&](int kt, int buf) {
        char* base = lds + buf * 10240;
#pragma unroll
        for (int i = 0; i < 2; ++i) {
            int r  = w * 32 + i * 16 + (lane >> 2);
            int sg = (lane & 3) ^ (r & 3);
            const f16* g = hist + (size_t)(r0 + r) * H_ + kt * 32 + sg * 8;
            gl_lds16(g, base + (size_t)(w * 32 + i * 16) * 64);
        }
    };
    auto stB = [&](int kt, int buf) {
        char* base = lds + 8192 + buf * 10240;
        if (w < 2) {
            int r  = w * 16 + (lane >> 2);
            int sg = (lane & 3) ^ (r & 3);
            const f16* g = Wd16 + (size_t)(nb0 + r) * H_ + kt * 32 + sg * 8;
            gl_lds16(g, base + (size_t)(w * 16) * 64);
        }
    };

    f32x4 acc[2][2];
#pragma unroll
    for (int m = 0; m < 2; ++m)
#pragma unroll
        for (int n = 0; n < 2; ++n) acc[m][n] = (f32x4){0.f, 0.f, 0.f, 0.f};

    stA(0, 0); stB(0, 0);
    for (int kt = 0; kt < 32; ++kt) {
        __syncthreads();
        if (kt + 1 < 32) { stA(kt + 1, (kt + 1) & 1); stB(kt + 1, (kt + 1) & 1); }
        const char* bA = lds + (kt & 1) * 10240;
        const char* bB = lds + 8192 + (kt & 1) * 10240;
        f16x8 af[2], bf[2];
#pragma unroll
        for (int m = 0; m < 2; ++m) {
            int R = w * 32 + m * 16 + lx;
            af[m] = *(const f16x8*)(bA + R * 64 + ((quad ^ (R & 3)) * 16));
        }
#pragma unroll
        for (int n = 0; n < 2; ++n) {
            int R = n * 16 + lx;
            bf[n] = *(const f16x8*)(bB + R * 64 + ((quad ^ (R & 3)) * 16));
        }
#pragma unroll
        for (int m = 0; m < 2; ++m)
#pragma unroll
            for (int n = 0; n < 2; ++n)
                acc[m][n] = MFMA16(af[m], bf[n], acc[m][n]);
    }

#pragma unroll
    for (int n = 0; n < 2; ++n) {
        int nn = nb0 + n * 16 + lx;
        if (nn < OUT_) {
            float bv = bd[nn];
#pragma unroll
            for (int m = 0; m < 2; ++m)
#pragma unroll
                for (int r = 0; r < 4; ++r) {
                    int row = r0 + w * 32 + m * 16 + quad * 4 + r;
                    int tt = row >> 8, b = row & 255;
                    dout[(size_t)b * (T_ * OUT_) + (size_t)tt * OUT_ + nn] = acc[m][n][r] + bv;
                }
        }
    }
}

// ---------------- host launch ----------------

extern "C" void kernel_launch(void* const* d_in, const int* in_sizes, int n_in,
                              void* d_out, int out_size, void* d_ws, size_t ws_size,
                              hipStream_t stream) {
    const float* seq  = (const float*)d_in[0];
    const float* Wih1 = (const float*)d_in[1];
    const float* Whh1 = (const float*)d_in[2];
    const float* bih1 = (const float*)d_in[3];
    const float* bhh1 = (const float*)d_in[4];
    const float* Wih2 = (const float*)d_in[5];
    const float* Whh2 = (const float*)d_in[6];
    const float* bih2 = (const float*)d_in[7];
    const float* bhh2 = (const float*)d_in[8];
    const float* Wih3 = (const float*)d_in[9];
    const float* Whh3 = (const float*)d_in[10];
    const float* bih3 = (const float*)d_in[11];
    const float* bhh3 = (const float*)d_in[12];
    const float* Wd   = (const float*)d_in[13];
    const float* bd   = (const float*)d_in[14];
    const int*   cnum = (const int*)d_in[15];
    const int*   gnum = (const int*)d_in[16];

    // ---- workspace layout
    char* p = (char*)d_ws;
    f16*  W0   = (f16*)p;  p += (size_t)4096 * 160 * 2;          // 1.31 MB
    f16*  Wd16 = (f16*)p;  p += (size_t)160 * 1024 * 2;          // 0.33 MB
    f16*  WdT  = (f16*)p;  p += (size_t)1024 * 160 * 2;          // 0.33 MB
    f16*  Wfb  = (f16*)p;  p += (size_t)4096 * 1024 * 2;         // 8.39 MB
    float* bias_comb = (float*)p; p += (size_t)3 * 4096 * 4;     // 48 KB
    float* bfb = (float*)p; p += (size_t)4096 * 4;               // 16 KB
    f16*  hist = (f16*)p;  p += (size_t)100 * BH * 2;            // 52.4 MB
    // zero region start: h01pkA + h2pkA + c_st (contiguous)
    f16*  h01pkA = (f16*)p; p += (size_t)2 * BH * 2;             // 1.05 MB
    f16*  h2pkA  = (f16*)p; p += (size_t)BH * 2;                 // 0.52 MB
    float* c_st  = (float*)p; p += (size_t)3 * BH * 4;           // 3.15 MB
    f16*  h01pkB = (f16*)p; p += (size_t)2 * BH * 2;             // 1.05 MB
    f16*  h2pkB  = (f16*)p; p += (size_t)BH * 2;                 // 0.52 MB
    f16*  Wpk   = (f16*)p; p += (size_t)6 * 64 * 32 * 2048 * 2;  // 50.3 MB
    f16*  W0pk  = (f16*)p; p += (size_t)64 * 5 * 2048 * 2;       // 1.31 MB
    f16*  seqpk = (f16*)p; p += (size_t)T_ * 5 * 256 * 32 * 2;   // 8.19 MB

    const int zero_floats = (int)(((size_t)3 * BH * 2 + (size_t)3 * BH * 4) / 4);

    // ---- prep
    conv_pad<<<dim3(1, 4096), 256, 0, stream>>>(Wih1, W0, 4096, IN_, 160);
    conv_pad<<<dim3(4, 160), 256, 0, stream>>>(Wd, Wd16, OUT_, H_, H_);
    convT_kernel<<<dim3(1, 1024), 256, 0, stream>>>(Wd, WdT);
    bias_add_kernel<<<16, 256, 0, stream>>>(bih1, bhh1, bias_comb + 0 * 4096, 4096);
    bias_add_kernel<<<16, 256, 0, stream>>>(bih2, bhh2, bias_comb + 1 * 4096, 4096);
    bias_add_kernel<<<16, 256, 0, stream>>>(bih3, bhh3, bias_comb + 2 * 4096, 4096);
    bfb_kernel<<<16, 256, 0, stream>>>(Wih1, bd, bfb);
    wfb_mfma<<<dim3(32, 8), 256, 0, stream>>>(W0, WdT, Wfb);
    // packed weights: wsel {0:Whh1, 1:Wih2, 2:Whh2, 3:Wih3, 4:Whh3, 5:Wfb}
    pack_w<<<dim3(64, 32), 256, 0, stream>>>(Whh1, Wpk, 0);
    pack_w<<<dim3(64, 32), 256, 0, stream>>>(Wih2, Wpk, 1);
    pack_w<<<dim3(64, 32), 256, 0, stream>>>(Whh2, Wpk, 2);
    pack_w<<<dim3(64, 32), 256, 0, stream>>>(Wih3, Wpk, 3);
    pack_w<<<dim3(64, 32), 256, 0, stream>>>(Whh3, Wpk, 4);
    pack_wf16<<<dim3(64, 32), 256, 0, stream>>>(Wfb, Wpk, 5);
    pack_w0<<<dim3(64, 5), 256, 0, stream>>>(Wih1, W0pk);
    pack_seq<<<dim3(5, T_), 256, 0, stream>>>(seq, seqpk);
    zero_kernel<<<512, 256, 0, stream>>>((float*)h01pkA, zero_floats);

    f16 *h01C = h01pkA, *h01N = h01pkB, *h2P = h2pkA, *h2N = h2pkB;
    for (int t = 0; t < T_; ++t) {
        step_mfma<<<dim3(64, 8, 3), 128, 0, stream>>>(
            seqpk, h2P, h01C, h01N, h2N, hist + (size_t)t * BH, c_st,
            W0pk, Wpk, bias_comb, bfb, cnum, gnum, t);
        f16* tmp;
        tmp = h01C; h01C = h01N; h01N = tmp;
        tmp = h2P;  h2P  = h2N;  h2N  = tmp;
    }

    decode_mfma<<<dim3(200, 5), 256, 0, stream>>>(hist, Wd16, bd, (float*)d_out);
}

// Round 7
// 3679.494 us; speedup vs baseline: 1.0383x; 1.0383x over previous
//
#include <hip/hip_runtime.h>
#include <math.h>

// Problem constants
#define B_   256
#define T_   100
#define IN_  132
#define OUT_ 132
#define H_   1024
#define BH   ((size_t)B_ * H_)

typedef _Float16 f16;
typedef _Float16 f16x8 __attribute__((ext_vector_type(8)));
typedef float    f32x4 __attribute__((ext_vector_type(4)));

#define MFMA16(a, b, c) __builtin_amdgcn_mfma_f32_16x16x32_f16((a), (b), (c), 0, 0, 0)

#define AS1 __attribute__((address_space(1)))
#define AS3 __attribute__((address_space(3)))

__device__ __forceinline__ void gl_lds16(const void* g, void* l) {
    __builtin_amdgcn_global_load_lds((AS1 void*)g, (AS3 void*)l, 16, 0, 0);
}

__device__ __forceinline__ float sigmoidf_(float x) {
    return 1.0f / (1.0f + __expf(-x));
}
__device__ __forceinline__ float tanhf_(float x) {
    float e = __expf(2.0f * x);
    return 1.0f - 2.0f / (e + 1.0f);
}

// ---------------- prep kernels ----------------

__global__ void conv_pad(const float* __restrict__ src, f16* __restrict__ dst,
                         int src_rows, int src_k, int dst_k) {
    int k = blockIdx.x * 256 + threadIdx.x;
    int r = blockIdx.y;
    if (k >= dst_k) return;
    float v = (r < src_rows && k < src_k) ? src[(size_t)r * src_k + k] : 0.0f;
    dst[(size_t)r * dst_k + k] = (f16)v;
}

// WdT[m][k] = Wd[k][m], padded to k<160. grid (1, 1024), block 256
__global__ void convT_kernel(const float* __restrict__ Wd, f16* __restrict__ WdT) {
    int k = blockIdx.x * 256 + threadIdx.x;
    int m = blockIdx.y;
    if (k >= 160) return;
    float v = (k < IN_) ? Wd[(size_t)k * H_ + m] : 0.0f;
    WdT[(size_t)m * 160 + k] = (f16)v;
}

__global__ void bias_add_kernel(const float* __restrict__ a, const float* __restrict__ b,
                                float* __restrict__ dst, int n) {
    int i = blockIdx.x * 256 + threadIdx.x;
    if (i < n) dst[i] = a[i] + b[i];
}

// bfb[j] = sum_k Wih1[j][k] * bd[k]
__global__ void bfb_kernel(const float* __restrict__ Wih1, const float* __restrict__ bd,
                           float* __restrict__ bfb) {
    int j = blockIdx.x * 256 + threadIdx.x;
    if (j >= 4096) return;
    float s = 0.0f;
    for (int k = 0; k < IN_; ++k) s += Wih1[(size_t)j * IN_ + k] * bd[k];
    bfb[j] = s;
}

__global__ void zero_kernel(float* __restrict__ p, int n) {
    int i = blockIdx.x * blockDim.x + threadIdx.x;
    int st = gridDim.x * blockDim.x;
    for (; i < n; i += st) p[i] = 0.0f;
}

// Pack fp32 [4096][1024] weight into direct-fragment layout:
// Wpk[wsel][jt(64)][kk(32)][c(64)][64B], col c: gate=(c>>4)&3, jj=c&15,
// src row = gate*1024 + jt*16 + jj, k = kk*32 + ch*8 + e (plain order).
// grid (64 jt, 32 kk), block 256 (one thread = one 16B sub-chunk).
__global__ __launch_bounds__(256) void pack_w(const float* __restrict__ W,
                                              f16* __restrict__ Wpk, int wsel) {
    int jt = blockIdx.x, kk = blockIdx.y;
    f16* dst = Wpk + (((size_t)wsel * 64 + jt) * 32 + kk) * 2048;
    int u = threadIdx.x;
    int c = u >> 2, ch = u & 3;
    int row = ((c >> 4) & 3) * 1024 + jt * 16 + (c & 15);
    const float* s = W + (size_t)row * 1024 + kk * 32 + ch * 8;
    f16x8 v;
#pragma unroll
    for (int e = 0; e < 8; ++e) v[e] = (f16)s[e];
    *(f16x8*)(dst + (size_t)c * 32 + ch * 8) = v;
}

// Same but f16 source (for Wfb [4096][1024]).
__global__ __launch_bounds__(256) void pack_wf16(const f16* __restrict__ W,
                                                 f16* __restrict__ Wpk, int wsel) {
    int jt = blockIdx.x, kk = blockIdx.y;
    f16* dst = Wpk + (((size_t)wsel * 64 + jt) * 32 + kk) * 2048;
    int u = threadIdx.x;
    int c = u >> 2, ch = u & 3;
    int row = ((c >> 4) & 3) * 1024 + jt * 16 + (c & 15);
    f16x8 v = *(const f16x8*)(W + (size_t)row * 1024 + kk * 32 + ch * 8);
    *(f16x8*)(dst + (size_t)c * 32 + ch * 8) = v;
}

// Pack Wih1 fp32 [4096][132] -> W0pk[jt(64)][kk(5)][2048], k padded to 160.
// grid (64 jt, 5 kk), block 256.
__global__ __launch_bounds__(256) void pack_w0(const float* __restrict__ W,
                                               f16* __restrict__ W0pk) {
    int jt = blockIdx.x, kk = blockIdx.y;
    f16* dst = W0pk + ((size_t)jt * 5 + kk) * 2048;
    int u = threadIdx.x;
    int c = u >> 2, ch = u & 3;
    int row = ((c >> 4) & 3) * 1024 + jt * 16 + (c & 15);
    f16x8 v;
#pragma unroll
    for (int e = 0; e < 8; ++e) {
        int k = kk * 32 + ch * 8 + e;
        v[e] = (f16)((k < IN_) ? W[(size_t)row * IN_ + k] : 0.0f);
    }
    *(f16x8*)(dst + (size_t)c * 32 + ch * 8) = v;
}

// Pack seq fp32 [B][T][IN] -> seqpk[t][kk(5)][256 b][32] f16. grid (5, 100), block 256.
__global__ __launch_bounds__(256) void pack_seq(const float* __restrict__ seq,
                                                f16* __restrict__ seqpk) {
    int kt = blockIdx.x, t = blockIdx.y;
    int b = threadIdx.x;
    f16* d = seqpk + (((size_t)t * 5 + kt) * 256 + b) * 32;
#pragma unroll
    for (int ch = 0; ch < 4; ++ch) {
        f16x8 v;
#pragma unroll
        for (int e = 0; e < 8; ++e) {
            int k = kt * 32 + ch * 8 + e;
            v[e] = (f16)((k < IN_) ? seq[((size_t)b * T_ + t) * IN_ + k] : 0.0f);
        }
        *(f16x8*)(d + ch * 8) = v;
    }
}

// Wfb = W0(fp16,[4096][160]) @ WdT(fp16,[1024][160])^T -> [4096][1024] fp16
// grid (32 m-tiles, 8 n-tiles), block 256 (4 waves 2x2 of 64x64). One-time prep.
__global__ __launch_bounds__(256) void wfb_mfma(
    const f16* __restrict__ W0, const f16* __restrict__ WdT, f16* __restrict__ Wfb)
{
    const int m0 = blockIdx.x * 128;
    const int n0 = blockIdx.y * 128;
    const int tid  = threadIdx.x;
    const int lane = tid & 63;
    const int w    = tid >> 6;
    const int lx   = lane & 15;
    const int quad = lane >> 4;
    const int wrow = w >> 1, wcol = w & 1;

    __shared__ __align__(16) char lds[32768];   // 2 x (A 8KB + B 8KB)

    auto stA = [&](int kt, int buf) {
        char* base = lds + buf * 16384;
#pragma unroll
        for (int i = 0; i < 2; ++i) {
            int r  = w * 32 + i * 16 + (lane >> 2);
            int sg = (lane & 3) ^ (r & 3);
            const f16* g = W0 + (size_t)(m0 + r) * 160 + kt * 32 + sg * 8;
            gl_lds16(g, base + (size_t)(w * 32 + i * 16) * 64);
        }
    };
    auto stB = [&](int kt, int buf) {
        char* base = lds + 8192 + buf * 16384;
#pragma unroll
        for (int i = 0; i < 2; ++i) {
            int r  = w * 32 + i * 16 + (lane >> 2);
            int sg = (lane & 3) ^ (r & 3);
            const f16* g = WdT + (size_t)(n0 + r) * 160 + kt * 32 + sg * 8;
            gl_lds16(g, base + (size_t)(w * 32 + i * 16) * 64);
        }
    };

    f32x4 acc[4][4];
#pragma unroll
    for (int m = 0; m < 4; ++m)
#pragma unroll
        for (int n = 0; n < 4; ++n) acc[m][n] = (f32x4){0.f, 0.f, 0.f, 0.f};

    stA(0, 0); stB(0, 0);
    for (int kt = 0; kt < 5; ++kt) {
        __syncthreads();
        if (kt + 1 < 5) { stA(kt + 1, (kt + 1) & 1); stB(kt + 1, (kt + 1) & 1); }
        const char* bA = lds + (kt & 1) * 16384;
        const char* bB = lds + 8192 + (kt & 1) * 16384;
        f16x8 af[4], bf[4];
#pragma unroll
        for (int m = 0; m < 4; ++m) {
            int R = wrow * 64 + m * 16 + lx;
            af[m] = *(const f16x8*)(bA + R * 64 + ((quad ^ (R & 3)) * 16));
        }
#pragma unroll
        for (int n = 0; n < 4; ++n) {
            int R = wcol * 64 + n * 16 + lx;
            bf[n] = *(const f16x8*)(bB + R * 64 + ((quad ^ (R & 3)) * 16));
        }
#pragma unroll
        for (int m = 0; m < 4; ++m)
#pragma unroll
            for (int n = 0; n < 4; ++n)
                acc[m][n] = MFMA16(af[m], bf[n], acc[m][n]);
    }

#pragma unroll
    for (int m = 0; m < 4; ++m)
#pragma unroll
        for (int n = 0; n < 4; ++n)
#pragma unroll
            for (int r = 0; r < 4; ++r) {
                int row = m0 + wrow * 64 + m * 16 + quad * 4 + r;
                int col = n0 + wcol * 64 + n * 16 + lx;
                Wfb[(size_t)row * H_ + col] = (f16)acc[m][n][r];
            }
}

// ---------------- fused per-step kernel (asm-pipelined direct-VGPR) ----------------
// grid (64 jt(16 j), 8 mb(32 batch), 3 cells), block 128 = 2 waves, K-split.
// Inner loop: 3 rotating register stages loaded via asm volatile
// global_load_dwordx4 (un-sinkable by the compiler), ordered with explicit
// s_waitcnt vmcnt(12/6/0) + sched_barrier(0) fences => 18 outstanding 1KB loads
// per wave at all times. This is the MLP every C++-load variant lost to the
// scheduler (R5/R6 VGPR counts proved the stages were collapsed).
__global__ __launch_bounds__(128, 3) void step_mfma(
    const f16* __restrict__ seqpk,    // [T][5][256][32]
    const f16* __restrict__ h2pkP,    // [32][256][32] prev h2 packed (zeros at t=0)
    const f16* __restrict__ h01pkC,   // [2][32][256][32] old h0,h1 packed
    f16* __restrict__ h01pkN,         // [2][32][256][32] new h0,h1 packed
    f16* __restrict__ h2pkN,          // [32][256][32] new h2 packed
    f16* __restrict__ histN,          // [256][1024] linear h2 for decode (hist + t*BH)
    float* __restrict__ c_st,         // [3][B][H]
    const f16* __restrict__ W0pk,     // [64][5][2048]
    const f16* __restrict__ Wpk,      // [6][64][32][2048]
    const float* __restrict__ bias_comb,  // [3][4096]
    const float* __restrict__ bfb,        // [4096]
    const int* __restrict__ cnum, const int* __restrict__ gnum,
    int t)
{
    const int jt   = blockIdx.x;
    const int mb   = blockIdx.y;       // 8 tiles of 32 batch rows
    const int l    = blockIdx.z;
    const int tid  = threadIdx.x;
    const int lane = tid & 63;
    const int w    = tid >> 6;         // 0/1 : K-split half
    const int lx   = lane & 15;
    const int quad = lane >> 4;

    __shared__ float ex[2][4][4][64];  // 8 KB: partial for dst-wave's own rows

    // ---- operand decode (byte pointers; per-kk strides: A 16KB, B 4KB)
    bool use_gt = false;
    int n0 = 32;
    const char *A0 = nullptr, *B0 = nullptr;
    const char* wbase = (const char*)Wpk + (size_t)jt * 131072;   // + wsel*8MB
    if (l == 0) {
        int cn = cnum[0], gn = gnum[0];
        use_gt = (t % (cn + gn)) < gn;
        if (use_gt)      { A0 = (const char*)(seqpk + (size_t)t * 40960);
                           B0 = (const char*)(W0pk + (size_t)jt * 10240); n0 = 5; }
        else if (t == 0) { n0 = 0; }
        else             { A0 = (const char*)h2pkP; B0 = wbase + (size_t)5 * 8388608; }
    } else if (l == 1) { A0 = (const char*)h01pkC;        B0 = wbase + (size_t)1 * 8388608; }
    else               { A0 = (const char*)(h01pkC + BH); B0 = wbase + (size_t)3 * 8388608; }
    const char* A1 = (l == 0) ? (const char*)h01pkC
                   : (l == 1) ? (const char*)(h01pkC + BH) : (const char*)h2pkP;
    const char* B1 = wbase + (size_t)((l == 0) ? 0 : (l == 1) ? 2 : 4) * 8388608;
    const int ntot = n0 + 32;
    const int nh = (ntot + 1) >> 1;
    const int lo = w ? nh : 0;
    const int hi = w ? ntot : nh;
    const int n  = hi - lo;

    const int aoff = (mb * 32 + lx) * 64 + quad * 16;
    const int boff = lx * 64 + quad * 16;

    f32x4 acc[2][4];
#pragma unroll
    for (int m = 0; m < 2; ++m)
#pragma unroll
        for (int nn = 0; nn < 4; ++nn) acc[m][nn] = (f32x4){0.f, 0.f, 0.f, 0.f};

    // ---- 3 rotating named register stages (6 x f16x8 = 24 VGPR each)
    struct Stg { f16x8 A0v, A1v, B0v, B1v, B2v, B3v; };
    Stg s0, s1, s2;

    auto LD = [&](Stg& s, int itx) {
        int kk; const char *pa, *pb;
        if (itx < n0) { kk = itx;      pa = A0; pb = B0; }
        else          { kk = itx - n0; pa = A1; pb = B1; }
        pa += (size_t)kk * 16384 + aoff;
        pb += (size_t)kk * 4096 + boff;
        // asm volatile: compiler cannot sink these to point-of-use.
        asm volatile("global_load_dwordx4 %0, %1, off"             : "=v"(s.A0v) : "v"(pa));
        asm volatile("global_load_dwordx4 %0, %1, off offset:1024" : "=v"(s.A1v) : "v"(pa));
        asm volatile("global_load_dwordx4 %0, %1, off"             : "=v"(s.B0v) : "v"(pb));
        asm volatile("global_load_dwordx4 %0, %1, off offset:1024" : "=v"(s.B1v) : "v"(pb));
        asm volatile("global_load_dwordx4 %0, %1, off offset:2048" : "=v"(s.B2v) : "v"(pb));
        asm volatile("global_load_dwordx4 %0, %1, off offset:3072" : "=v"(s.B3v) : "v"(pb));
    };
    auto MF = [&](Stg& s) {
        __builtin_amdgcn_s_setprio(1);
        acc[0][0] = MFMA16(s.A0v, s.B0v, acc[0][0]);
        acc[0][1] = MFMA16(s.A0v, s.B1v, acc[0][1]);
        acc[0][2] = MFMA16(s.A0v, s.B2v, acc[0][2]);
        acc[0][3] = MFMA16(s.A0v, s.B3v, acc[0][3]);
        acc[1][0] = MFMA16(s.A1v, s.B0v, acc[1][0]);
        acc[1][1] = MFMA16(s.A1v, s.B1v, acc[1][1]);
        acc[1][2] = MFMA16(s.A1v, s.B2v, acc[1][2]);
        acc[1][3] = MFMA16(s.A1v, s.B3v, acc[1][3]);
        __builtin_amdgcn_s_setprio(0);
    };
    // one pipeline step: issue stage kt+2 into SL, wait for stage kt, MFMA it (SU)
    auto STEP = [&](Stg& SU, Stg& SL, int kt) {
        if (kt + 2 < n) {
            LD(SL, lo + kt + 2);
            asm volatile("s_waitcnt vmcnt(12)" ::: "memory");
        } else if (kt + 1 < n) {
            asm volatile("s_waitcnt vmcnt(6)" ::: "memory");
        } else {
            asm volatile("s_waitcnt vmcnt(0)" ::: "memory");
        }
        __builtin_amdgcn_sched_barrier(0);   // rule #18: pin MFMA after waitcnt
        MF(SU);
        __builtin_amdgcn_sched_barrier(0);
    };

    if (n > 0) LD(s0, lo);
    if (n > 1) LD(s1, lo + 1);

    int kt = 0;
    while (kt + 3 <= n) {
        STEP(s0, s2, kt); ++kt;
        STEP(s1, s0, kt); ++kt;
        STEP(s2, s1, kt); ++kt;
    }
    if (kt < n) { STEP(s0, s2, kt); ++kt; }
    if (kt < n) { STEP(s1, s0, kt); ++kt; }

    // ---- K-combine: each wave publishes the OTHER wave's rows (m = 1-w)
    if (w == 0) {
#pragma unroll
        for (int nn = 0; nn < 4; ++nn)
#pragma unroll
            for (int r = 0; r < 4; ++r) ex[1][nn][r][lane] = acc[1][nn][r];
    } else {
#pragma unroll
        for (int nn = 0; nn < 4; ++nn)
#pragma unroll
            for (int r = 0; r < 4; ++r) ex[0][nn][r][lane] = acc[0][nn][r];
    }
    __syncthreads();

    f32x4 fa[4];
    if (w == 0) {
#pragma unroll
        for (int nn = 0; nn < 4; ++nn) fa[nn] = acc[0][nn];
    } else {
#pragma unroll
        for (int nn = 0; nn < 4; ++nn) fa[nn] = acc[1][nn];
    }

    // ---- lane-local LSTM epilogue (wave w owns rows mb*32 + w*16 .. +15)
    const int j = jt * 16 + lx;
    const float* bc = bias_comb + l * 4096;
    const bool addfb = (l == 0 && !use_gt && t > 0);
    float bi  = bc[j]        + (addfb ? bfb[j]        : 0.f);
    float bff = bc[1024 + j] + (addfb ? bfb[1024 + j] : 0.f);
    float bg  = bc[2048 + j] + (addfb ? bfb[2048 + j] : 0.f);
    float bo  = bc[3072 + j] + (addfb ? bfb[3072 + j] : 0.f);
#pragma unroll
    for (int r = 0; r < 4; ++r) {
        int b = mb * 32 + w * 16 + quad * 4 + r;
        float gi = fa[0][r] + ex[w][0][r][lane] + bi;
        float gf = fa[1][r] + ex[w][1][r][lane] + bff;
        float gg = fa[2][r] + ex[w][2][r][lane] + bg;
        float go = fa[3][r] + ex[w][3][r][lane] + bo;
        size_t ix = ((size_t)l * B_ + b) * H_ + j;
        float cn = sigmoidf_(gf) * c_st[ix] + sigmoidf_(gi) * tanhf_(gg);
        c_st[ix] = cn;
        float hv = sigmoidf_(go) * tanhf_(cn);
        f16 hv16 = (f16)hv;
        size_t pix = ((size_t)(j >> 5) * 256 + b) * 32 + (j & 31);   // packed
        if (l == 2) { h2pkN[pix] = hv16; histN[(size_t)b * H_ + j] = hv16; }
        else        h01pkN[(size_t)l * BH + pix] = hv16;
    }
}

// ---------------- final batched decoder ----------------
// out[b][t][n] = hist[t][b][:] @ Wd^T + bd. M=25600 rows (t*256+b), N=160(132), K=1024.
// grid (200, 5), block 256 (4 waves stacked on M; tile 128x32).
__global__ __launch_bounds__(256) void decode_mfma(
    const f16* __restrict__ hist,   // [100][256][1024]
    const f16* __restrict__ Wd16,   // [160][1024]
    const float* __restrict__ bd,   // [132]
    float* __restrict__ dout)       // [256][T*132]
{
    const int r0  = blockIdx.x * 128;
    const int nb0 = blockIdx.y * 32;
    const int tid  = threadIdx.x;
    const int lane = tid & 63;
    const int w    = tid >> 6;
    const int lx   = lane & 15;
    const int quad = lane >> 4;

    __shared__ __align__(16) char lds[20480];   // 2 x (A 8KB + B 2KB)

    auto stA = [&](int kt, int buf) {
        char* base = lds + buf * 10240;
#pragma unroll
        for (int i = 0; i < 2; ++i) {
            int r  = w * 32 + i * 16 + (lane >> 2);
            int sg = (lane & 3) ^ (r & 3);
            const f16* g = hist + (size_t)(r0 + r) * H_ + kt * 32 + sg * 8;
            gl_lds16(g, base + (size_t)(w * 32 + i * 16) * 64);
        }
    };
    auto stB = [&](int kt, int buf) {
        char* base = lds + 8192 + buf * 10240;
        if (w < 2) {
            int r  = w * 16 + (lane >> 2);
            int sg = (lane & 3) ^ (r & 3);
            const f16* g = Wd16 + (size_t)(nb0 + r) * H_ + kt * 32 + sg * 8;
            gl_lds16(g, base + (size_t)(w * 16) * 64);
        }
    };

    f32x4 acc[2][2];
#pragma unroll
    for (int m = 0; m < 2; ++m)
#pragma unroll
        for (int n = 0; n < 2; ++n) acc[m][n] = (f32x4){0.f, 0.f, 0.f, 0.f};

    stA(0, 0); stB(0, 0);
    for (int kt = 0; kt < 32; ++kt) {
        __syncthreads();
        if (kt + 1 < 32) { stA(kt + 1, (kt + 1) & 1); stB(kt + 1, (kt + 1) & 1); }
        const char* bA = lds + (kt & 1) * 10240;
        const char* bB = lds + 8192 + (kt & 1) * 10240;
        f16x8 af[2], bf[2];
#pragma unroll
        for (int m = 0; m < 2; ++m) {
            int R = w * 32 + m * 16 + lx;
            af[m] = *(const f16x8*)(bA + R * 64 + ((quad ^ (R & 3)) * 16));
        }
#pragma unroll
        for (int n = 0; n < 2; ++n) {
            int R = n * 16 + lx;
            bf[n] = *(const f16x8*)(bB + R * 64 + ((quad ^ (R & 3)) * 16));
        }
#pragma unroll
        for (int m = 0; m < 2; ++m)
#pragma unroll
            for (int n = 0; n < 2; ++n)
                acc[m][n] = MFMA16(af[m], bf[n], acc[m][n]);
    }

#pragma unroll
    for (int n = 0; n < 2; ++n) {
        int nn = nb0 + n * 16 + lx;
        if (nn < OUT_) {
            float bv = bd[nn];
#pragma unroll
            for (int m = 0; m < 2; ++m)
#pragma unroll
                for (int r = 0; r < 4; ++r) {
                    int row = r0 + w * 32 + m * 16 + quad * 4 + r;
                    int tt = row >> 8, b = row & 255;
                    dout[(size_t)b * (T_ * OUT_) + (size_t)tt * OUT_ + nn] = acc[m][n][r] + bv;
                }
        }
    }
}

// ---------------- host launch ----------------

extern "C" void kernel_launch(void* const* d_in, const int* in_sizes, int n_in,
                              void* d_out, int out_size, void* d_ws, size_t ws_size,
                              hipStream_t stream) {
    const float* seq  = (const float*)d_in[0];
    const float* Wih1 = (const float*)d_in[1];
    const float* Whh1 = (const float*)d_in[2];
    const float* bih1 = (const float*)d_in[3];
    const float* bhh1 = (const float*)d_in[4];
    const float* Wih2 = (const float*)d_in[5];
    const float* Whh2 = (const float*)d_in[6];
    const float* bih2 = (const float*)d_in[7];
    const float* bhh2 = (const float*)d_in[8];
    const float* Wih3 = (const float*)d_in[9];
    const float* Whh3 = (const float*)d_in[10];
    const float* bih3 = (const float*)d_in[11];
    const float* bhh3 = (const float*)d_in[12];
    const float* Wd   = (const float*)d_in[13];
    const float* bd   = (const float*)d_in[14];
    const int*   cnum = (const int*)d_in[15];
    const int*   gnum = (const int*)d_in[16];

    // ---- workspace layout
    char* p = (char*)d_ws;
    f16*  W0   = (f16*)p;  p += (size_t)4096 * 160 * 2;          // 1.31 MB
    f16*  Wd16 = (f16*)p;  p += (size_t)160 * 1024 * 2;          // 0.33 MB
    f16*  WdT  = (f16*)p;  p += (size_t)1024 * 160 * 2;          // 0.33 MB
    f16*  Wfb  = (f16*)p;  p += (size_t)4096 * 1024 * 2;         // 8.39 MB
    float* bias_comb = (float*)p; p += (size_t)3 * 4096 * 4;     // 48 KB
    float* bfb = (float*)p; p += (size_t)4096 * 4;               // 16 KB
    f16*  hist = (f16*)p;  p += (size_t)100 * BH * 2;            // 52.4 MB
    // zero region start: h01pkA + h2pkA + c_st (contiguous)
    f16*  h01pkA = (f16*)p; p += (size_t)2 * BH * 2;             // 1.05 MB
    f16*  h2pkA  = (f16*)p; p += (size_t)BH * 2;                 // 0.52 MB
    float* c_st  = (float*)p; p += (size_t)3 * BH * 4;           // 3.15 MB
    f16*  h01pkB = (f16*)p; p += (size_t)2 * BH * 2;             // 1.05 MB
    f16*  h2pkB  = (f16*)p; p += (size_t)BH * 2;                 // 0.52 MB
    f16*  Wpk   = (f16*)p; p += (size_t)6 * 64 * 32 * 2048 * 2;  // 50.3 MB
    f16*  W0pk  = (f16*)p; p += (size_t)64 * 5 * 2048 * 2;       // 1.31 MB
    f16*  seqpk = (f16*)p; p += (size_t)T_ * 5 * 256 * 32 * 2;   // 8.19 MB

    const int zero_floats = (int)(((size_t)3 * BH * 2 + (size_t)3 * BH * 4) / 4);

    // ---- prep
    conv_pad<<<dim3(1, 4096), 256, 0, stream>>>(Wih1, W0, 4096, IN_, 160);
    conv_pad<<<dim3(4, 160), 256, 0, stream>>>(Wd, Wd16, OUT_, H_, H_);
    convT_kernel<<<dim3(1, 1024), 256, 0, stream>>>(Wd, WdT);
    bias_add_kernel<<<16, 256, 0, stream>>>(bih1, bhh1, bias_comb + 0 * 4096, 4096);
    bias_add_kernel<<<16, 256, 0, stream>>>(bih2, bhh2, bias_comb + 1 * 4096, 4096);
    bias_add_kernel<<<16, 256, 0, stream>>>(bih3, bhh3, bias_comb + 2 * 4096, 4096);
    bfb_kernel<<<16, 256, 0, stream>>>(Wih1, bd, bfb);
    wfb_mfma<<<dim3(32, 8), 256, 0, stream>>>(W0, WdT, Wfb);
    // packed weights: wsel {0:Whh1, 1:Wih2, 2:Whh2, 3:Wih3, 4:Whh3, 5:Wfb}
    pack_w<<<dim3(64, 32), 256, 0, stream>>>(Whh1, Wpk, 0);
    pack_w<<<dim3(64, 32), 256, 0, stream>>>(Wih2, Wpk, 1);
    pack_w<<<dim3(64, 32), 256, 0, stream>>>(Whh2, Wpk, 2);
    pack_w<<<dim3(64, 32), 256, 0, stream>>>(Wih3, Wpk, 3);
    pack_w<<<dim3(64, 32), 256, 0, stream>>>(Whh3, Wpk, 4);
    pack_wf16<<<dim3(64, 32), 256, 0, stream>>>(Wfb, Wpk, 5);
    pack_w0<<<dim3(64, 5), 256, 0, stream>>>(Wih1, W0pk);
    pack_seq<<<dim3(5, T_), 256, 0, stream>>>(seq, seqpk);
    zero_kernel<<<512, 256, 0, stream>>>((float*)h01pkA, zero_floats);

    f16 *h01C = h01pkA, *h01N = h01pkB, *h2P = h2pkA, *h2N = h2pkB;
    for (int t = 0; t < T_; ++t) {
        step_mfma<<<dim3(64, 8, 3), 128, 0, stream>>>(
            seqpk, h2P, h01C, h01N, h2N, hist + (size_t)t * BH, c_st,
            W0pk, Wpk, bias_comb, bfb, cnum, gnum, t);
        f16* tmp;
        tmp = h01C; h01C = h01N; h01N = tmp;
        tmp = h2P;  h2P  = h2N;  h2N  = tmp;
    }

    decode_mfma<<<dim3(200, 5), 256, 0, stream>>>(hist, Wd16, bd, (float*)d_out);
}

// Round 8
// 3331.938 us; speedup vs baseline: 1.1466x; 1.1043x over previous
//
#include <hip/hip_runtime.h>
#include <math.h>

// Problem constants
#define B_   256
#define T_   100
#define IN_  132
#define OUT_ 132
#define H_   1024
#define BH   ((size_t)B_ * H_)

typedef _Float16 f16;
typedef _Float16 f16x8 __attribute__((ext_vector_type(8)));
typedef float    f32x4 __attribute__((ext_vector_type(4)));

#define MFMA16(a, b, c) __builtin_amdgcn_mfma_f32_16x16x32_f16((a), (b), (c), 0, 0, 0)

#define AS1 __attribute__((address_space(1)))
#define AS3 __attribute__((address_space(3)))

__device__ __forceinline__ void gl_lds16(const void* g, void* l) {
    __builtin_amdgcn_global_load_lds((AS1 void*)g, (AS3 void*)l, 16, 0, 0);
}

__device__ __forceinline__ float sigmoidf_(float x) {
    return 1.0f / (1.0f + __expf(-x));
}
__device__ __forceinline__ float tanhf_(float x) {
    float e = __expf(2.0f * x);
    return 1.0f - 2.0f / (e + 1.0f);
}

// ---------------- prep kernels ----------------

__global__ void conv_pad(const float* __restrict__ src, f16* __restrict__ dst,
                         int src_rows, int src_k, int dst_k) {
    int k = blockIdx.x * 256 + threadIdx.x;
    int r = blockIdx.y;
    if (k >= dst_k) return;
    float v = (r < src_rows && k < src_k) ? src[(size_t)r * src_k + k] : 0.0f;
    dst[(size_t)r * dst_k + k] = (f16)v;
}

// WdT[m][k] = Wd[k][m], padded to k<160. grid (1, 1024), block 256
__global__ void convT_kernel(const float* __restrict__ Wd, f16* __restrict__ WdT) {
    int k = blockIdx.x * 256 + threadIdx.x;
    int m = blockIdx.y;
    if (k >= 160) return;
    float v = (k < IN_) ? Wd[(size_t)k * H_ + m] : 0.0f;
    WdT[(size_t)m * 160 + k] = (f16)v;
}

__global__ void bias_add_kernel(const float* __restrict__ a, const float* __restrict__ b,
                                float* __restrict__ dst, int n) {
    int i = blockIdx.x * 256 + threadIdx.x;
    if (i < n) dst[i] = a[i] + b[i];
}

// bfb[j] = sum_k Wih1[j][k] * bd[k]
__global__ void bfb_kernel(const float* __restrict__ Wih1, const float* __restrict__ bd,
                           float* __restrict__ bfb) {
    int j = blockIdx.x * 256 + threadIdx.x;
    if (j >= 4096) return;
    float s = 0.0f;
    for (int k = 0; k < IN_; ++k) s += Wih1[(size_t)j * IN_ + k] * bd[k];
    bfb[j] = s;
}

__global__ void zero_kernel(float* __restrict__ p, int n) {
    int i = blockIdx.x * blockDim.x + threadIdx.x;
    int st = gridDim.x * blockDim.x;
    for (; i < n; i += st) p[i] = 0.0f;
}

// Pack fp32 [4096][1024] weight into chunk layout:
// Wpk[wsel][jt(64)][kk(32)][c(64)][64B], col c: gate=(c>>4)&3, jj=c&15,
// src row = gate*1024 + jt*16 + jj, k = kk*32 + ch*8 + e (plain order).
// grid (64 jt, 32 kk), block 256 (one thread = one 16B sub-chunk).
__global__ __launch_bounds__(256) void pack_w(const float* __restrict__ W,
                                              f16* __restrict__ Wpk, int wsel) {
    int jt = blockIdx.x, kk = blockIdx.y;
    f16* dst = Wpk + (((size_t)wsel * 64 + jt) * 32 + kk) * 2048;
    int u = threadIdx.x;
    int c = u >> 2, ch = u & 3;
    int row = ((c >> 4) & 3) * 1024 + jt * 16 + (c & 15);
    const float* s = W + (size_t)row * 1024 + kk * 32 + ch * 8;
    f16x8 v;
#pragma unroll
    for (int e = 0; e < 8; ++e) v[e] = (f16)s[e];
    *(f16x8*)(dst + (size_t)c * 32 + ch * 8) = v;
}

// Same but f16 source (for Wfb [4096][1024]).
__global__ __launch_bounds__(256) void pack_wf16(const f16* __restrict__ W,
                                                 f16* __restrict__ Wpk, int wsel) {
    int jt = blockIdx.x, kk = blockIdx.y;
    f16* dst = Wpk + (((size_t)wsel * 64 + jt) * 32 + kk) * 2048;
    int u = threadIdx.x;
    int c = u >> 2, ch = u & 3;
    int row = ((c >> 4) & 3) * 1024 + jt * 16 + (c & 15);
    f16x8 v = *(const f16x8*)(W + (size_t)row * 1024 + kk * 32 + ch * 8);
    *(f16x8*)(dst + (size_t)c * 32 + ch * 8) = v;
}

// Pack Wih1 fp32 [4096][132] -> W0pk[jt(64)][kk(5)][2048], k padded to 160.
// grid (64 jt, 5 kk), block 256.
__global__ __launch_bounds__(256) void pack_w0(const float* __restrict__ W,
                                               f16* __restrict__ W0pk) {
    int jt = blockIdx.x, kk = blockIdx.y;
    f16* dst = W0pk + ((size_t)jt * 5 + kk) * 2048;
    int u = threadIdx.x;
    int c = u >> 2, ch = u & 3;
    int row = ((c >> 4) & 3) * 1024 + jt * 16 + (c & 15);
    f16x8 v;
#pragma unroll
    for (int e = 0; e < 8; ++e) {
        int k = kk * 32 + ch * 8 + e;
        v[e] = (f16)((k < IN_) ? W[(size_t)row * IN_ + k] : 0.0f);
    }
    *(f16x8*)(dst + (size_t)c * 32 + ch * 8) = v;
}

// Pack seq fp32 [B][T][IN] -> seqpk[t][kk(5)][256 b][32] f16. grid (5, 100), block 256.
__global__ __launch_bounds__(256) void pack_seq(const float* __restrict__ seq,
                                                f16* __restrict__ seqpk) {
    int kt = blockIdx.x, t = blockIdx.y;
    int b = threadIdx.x;
    f16* d = seqpk + (((size_t)t * 5 + kt) * 256 + b) * 32;
#pragma unroll
    for (int ch = 0; ch < 4; ++ch) {
        f16x8 v;
#pragma unroll
        for (int e = 0; e < 8; ++e) {
            int k = kt * 32 + ch * 8 + e;
            v[e] = (f16)((k < IN_) ? seq[((size_t)b * T_ + t) * IN_ + k] : 0.0f);
        }
        *(f16x8*)(d + ch * 8) = v;
    }
}

// Wfb = W0(fp16,[4096][160]) @ WdT(fp16,[1024][160])^T -> [4096][1024] fp16
// grid (32 m-tiles, 8 n-tiles), block 256 (4 waves 2x2 of 64x64). One-time prep.
__global__ __launch_bounds__(256) void wfb_mfma(
    const f16* __restrict__ W0, const f16* __restrict__ WdT, f16* __restrict__ Wfb)
{
    const int m0 = blockIdx.x * 128;
    const int n0 = blockIdx.y * 128;
    const int tid  = threadIdx.x;
    const int lane = tid & 63;
    const int w    = tid >> 6;
    const int lx   = lane & 15;
    const int quad = lane >> 4;
    const int wrow = w >> 1, wcol = w & 1;

    __shared__ __align__(16) char lds[32768];   // 2 x (A 8KB + B 8KB)

    auto stA = [&](int kt, int buf) {
        char* base = lds + buf * 16384;
#pragma unroll
        for (int i = 0; i < 2; ++i) {
            int r  = w * 32 + i * 16 + (lane >> 2);
            int sg = (lane & 3) ^ (r & 3);
            const f16* g = W0 + (size_t)(m0 + r) * 160 + kt * 32 + sg * 8;
            gl_lds16(g, base + (size_t)(w * 32 + i * 16) * 64);
        }
    };
    auto stB = [&](int kt, int buf) {
        char* base = lds + 8192 + buf * 16384;
#pragma unroll
        for (int i = 0; i < 2; ++i) {
            int r  = w * 32 + i * 16 + (lane >> 2);
            int sg = (lane & 3) ^ (r & 3);
            const f16* g = WdT + (size_t)(n0 + r) * 160 + kt * 32 + sg * 8;
            gl_lds16(g, base + (size_t)(w * 32 + i * 16) * 64);
        }
    };

    f32x4 acc[4][4];
#pragma unroll
    for (int m = 0; m < 4; ++m)
#pragma unroll
        for (int n = 0; n < 4; ++n) acc[m][n] = (f32x4){0.f, 0.f, 0.f, 0.f};

    stA(0, 0); stB(0, 0);
    for (int kt = 0; kt < 5; ++kt) {
        __syncthreads();
        if (kt + 1 < 5) { stA(kt + 1, (kt + 1) & 1); stB(kt + 1, (kt + 1) & 1); }
        const char* bA = lds + (kt & 1) * 16384;
        const char* bB = lds + 8192 + (kt & 1) * 16384;
        f16x8 af[4], bf[4];
#pragma unroll
        for (int m = 0; m < 4; ++m) {
            int R = wrow * 64 + m * 16 + lx;
            af[m] = *(const f16x8*)(bA + R * 64 + ((quad ^ (R & 3)) * 16));
        }
#pragma unroll
        for (int n = 0; n < 4; ++n) {
            int R = wcol * 64 + n * 16 + lx;
            bf[n] = *(const f16x8*)(bB + R * 64 + ((quad ^ (R & 3)) * 16));
        }
#pragma unroll
        for (int m = 0; m < 4; ++m)
#pragma unroll
            for (int n = 0; n < 4; ++n)
                acc[m][n] = MFMA16(af[m], bf[n], acc[m][n]);
    }

#pragma unroll
    for (int m = 0; m < 4; ++m)
#pragma unroll
        for (int n = 0; n < 4; ++n)
#pragma unroll
            for (int r = 0; r < 4; ++r) {
                int row = m0 + wrow * 64 + m * 16 + quad * 4 + r;
                int col = n0 + wcol * 64 + n * 16 + lx;
                Wfb[(size_t)row * H_ + col] = (f16)acc[m][n][r];
            }
}

// ---------------- fused per-step kernel (full-batch, B-redundancy-1) ----------------
// grid (64 jt(16 j), 3 cells) = 192 blocks x 512 thr = 2 K-teams x 4 M-waves.
// Block tile: FULL batch 256 x 64 cols (16 j x 4 gates; col c = n*16+lx -> gate=n,
// j = jt*16+lx -> lane-local LSTM). Weights cross L2 exactly ONCE per step
// (B staged in LDS, shared by the team's 4 M-waves). Per team: 3-buffer ring
// (A 16KB + B 4KB per K-chunk), 5 contiguous 1KB gl_lds per wave per chunk,
// counted vmcnt(5), ONE raw barrier per chunk (m201-style). Teams split K and
// combine via a post-loop LDS exchange reusing the dead ring space.
__global__ __launch_bounds__(512) void step_mfma(
    const f16* __restrict__ seqpk,    // [T][5][256][32]
    const f16* __restrict__ h2pkP,    // [32][256][32] prev h2 packed (zeros at t=0)
    const f16* __restrict__ h01pkC,   // [2][32][256][32] old h0,h1 packed
    f16* __restrict__ h01pkN,         // [2][32][256][32] new h0,h1 packed
    f16* __restrict__ h2pkN,          // [32][256][32] new h2 packed
    f16* __restrict__ histN,          // [256][1024] linear h2 for decode (hist + t*BH)
    float* __restrict__ c_st,         // [3][B][H]
    const f16* __restrict__ W0pk,     // [64][5][2048]
    const f16* __restrict__ Wpk,      // [6][64][32][2048]
    const float* __restrict__ bias_comb,  // [3][4096]
    const float* __restrict__ bfb,        // [4096]
    const int* __restrict__ cnum, const int* __restrict__ gnum,
    int t)
{
    extern __shared__ __align__(16) char lds[];   // 122880 B: 2 teams x 3 x 20KB

    const int jt   = blockIdx.x;
    const int l    = blockIdx.y;
    const int tid  = threadIdx.x;
    const int lane = tid & 63;
    const int w    = tid >> 6;
    const int team = w >> 2;           // 0/1 : K-split half
    const int mw   = w & 3;            // M-quarter (64 batch rows)
    const int lx   = lane & 15;
    const int quad = lane >> 4;

    // ---- operand decode (byte pointers; chunk strides: A 16KB, B 4KB)
    bool use_gt = false;
    int n0 = 32;
    const char *A0 = nullptr, *B0 = nullptr;
    const char* wbase = (const char*)Wpk + (size_t)jt * 131072;   // + wsel*8MB
    if (l == 0) {
        int cn = cnum[0], gn = gnum[0];
        use_gt = (t % (cn + gn)) < gn;
        if (use_gt)      { A0 = (const char*)(seqpk + (size_t)t * 40960);
                           B0 = (const char*)(W0pk + (size_t)jt * 10240); n0 = 5; }
        else if (t == 0) { n0 = 0; }
        else             { A0 = (const char*)h2pkP; B0 = wbase + (size_t)5 * 8388608; }
    } else if (l == 1) { A0 = (const char*)h01pkC;        B0 = wbase + (size_t)1 * 8388608; }
    else               { A0 = (const char*)(h01pkC + BH); B0 = wbase + (size_t)3 * 8388608; }
    const char* A1 = (l == 0) ? (const char*)h01pkC
                   : (l == 1) ? (const char*)(h01pkC + BH) : (const char*)h2pkP;
    const char* B1 = wbase + (size_t)((l == 0) ? 0 : (l == 1) ? 2 : 4) * 8388608;
    const int ntot = n0 + 32;
    const int nh   = (ntot + 1) >> 1;       // block-uniform
    const int lo   = team ? nh : 0;
    const int hi   = team ? ntot : nh;
    const int n    = hi - lo;               // team iter count (team0 >= team1)
    const int nmax = nh;                    // loop trip count (uniform)

    char* tb = lds + team * 61440;          // team ring: 3 x 20KB

    // stage team-local chunk ktl into ring buffer `buf` (20KB: A 16KB | B 4KB).
    // 5 contiguous 1KB gl_lds per wave; XOR swizzle applied on per-lane source.
    auto stage = [&](int ktl, char* buf) {
        int itx = lo + ktl;
        int kk; const char *pa, *pb;
        if (itx < n0) { kk = itx;      pa = A0; pb = B0; }
        else          { kk = itx - n0; pa = A1; pb = B1; }
        pa += (size_t)kk * 16384;
        pb += (size_t)kk * 4096;
        const int s = lane & 3;
#pragma unroll
        for (int i = 0; i < 4; ++i) {
            int row16 = mw * 64 + i * 16;
            int r = row16 + (lane >> 2);
            gl_lds16(pa + r * 64 + ((s ^ (r & 3)) * 16), buf + row16 * 64);
        }
        {
            int c16 = mw * 16;
            int c = c16 + (lane >> 2);
            gl_lds16(pb + c * 64 + ((s ^ (c & 3)) * 16), buf + 16384 + c16 * 64);
        }
    };

    f32x4 acc[4][4];
#pragma unroll
    for (int m = 0; m < 4; ++m)
#pragma unroll
        for (int nn = 0; nn < 4; ++nn) acc[m][nn] = (f32x4){0.f, 0.f, 0.f, 0.f};

    if (n > 0) stage(0, tb);
    if (n > 1) stage(1, tb + 20480);

    // one iteration; p/pnext are compile-time ring slots (x3 unrolled loop)
    auto ITER = [&](int kt, int p, int pn) {
        const bool act = kt < n;
        if (act) {
            if (kt < n - 1) asm volatile("s_waitcnt vmcnt(5)" ::: "memory");
            else            asm volatile("s_waitcnt vmcnt(0)" ::: "memory");
        }
        __builtin_amdgcn_s_barrier();          // chunk kt visible to team

        f16x8 af[4], bf[4];
        if (act) {
            const char* bA = tb + p * 20480;
            const char* bB = bA + 16384;
#pragma unroll
            for (int m = 0; m < 4; ++m) {
                int R = mw * 64 + m * 16 + lx;
                af[m] = *(const f16x8*)(bA + R * 64 + ((quad ^ (R & 3)) * 16));
            }
#pragma unroll
            for (int nn = 0; nn < 4; ++nn) {
                int C = nn * 16 + lx;
                bf[nn] = *(const f16x8*)(bB + C * 64 + ((quad ^ (C & 3)) * 16));
            }
        }
        asm volatile("s_waitcnt lgkmcnt(0)" ::: "memory");
        __builtin_amdgcn_sched_barrier(0);

        if (act && kt + 2 < n) stage(kt + 2, tb + pn * 20480);

        if (act) {
            __builtin_amdgcn_s_setprio(1);
#pragma unroll
            for (int m = 0; m < 4; ++m)
#pragma unroll
                for (int nn = 0; nn < 4; ++nn)
                    acc[m][nn] = MFMA16(af[m], bf[nn], acc[m][nn]);
            __builtin_amdgcn_s_setprio(0);
        }
    };

    for (int kb = 0; kb < nmax; kb += 3) {
        ITER(kb, 0, 2);
        if (kb + 1 < nmax) ITER(kb + 1, 1, 0);
        if (kb + 2 < nmax) ITER(kb + 2, 2, 1);
    }

    // ---- K-combine via LDS exchange (reuses dead ring space; 64KB f32)
    __syncthreads();
    float* ex = (float*)lds;
    if (team == 1) {
#pragma unroll
        for (int m = 0; m < 4; ++m)
#pragma unroll
            for (int nn = 0; nn < 4; ++nn)
#pragma unroll
                for (int r = 0; r < 4; ++r) {
                    int row = mw * 64 + m * 16 + quad * 4 + r;
                    ex[(size_t)row * 64 + nn * 16 + lx] = acc[m][nn][r];
                }
    }
    __syncthreads();

    // ---- lane-local LSTM epilogue (team 0; wave mw owns rows mw*64..+63)
    if (team == 0) {
        const int j = jt * 16 + lx;
        const float* bc = bias_comb + l * 4096;
        const bool addfb = (l == 0 && !use_gt && t > 0);
        float bi  = bc[j]        + (addfb ? bfb[j]        : 0.f);
        float bff = bc[1024 + j] + (addfb ? bfb[1024 + j] : 0.f);
        float bg  = bc[2048 + j] + (addfb ? bfb[2048 + j] : 0.f);
        float bo  = bc[3072 + j] + (addfb ? bfb[3072 + j] : 0.f);
#pragma unroll
        for (int m = 0; m < 4; ++m) {
#pragma unroll
            for (int r = 0; r < 4; ++r) {
                int b = mw * 64 + m * 16 + quad * 4 + r;
                const float* eb = ex + (size_t)b * 64;
                float gi = acc[m][0][r] + eb[lx]      + bi;
                float gf = acc[m][1][r] + eb[16 + lx] + bff;
                float gg = acc[m][2][r] + eb[32 + lx] + bg;
                float go = acc[m][3][r] + eb[48 + lx] + bo;
                size_t ix = ((size_t)l * B_ + b) * H_ + j;
                float cn2 = sigmoidf_(gf) * c_st[ix] + sigmoidf_(gi) * tanhf_(gg);
                c_st[ix] = cn2;
                float hv = sigmoidf_(go) * tanhf_(cn2);
                f16 hv16 = (f16)hv;
                size_t pix = ((size_t)(j >> 5) * 256 + b) * 32 + (j & 31);   // packed
                if (l == 2) { h2pkN[pix] = hv16; histN[(size_t)b * H_ + j] = hv16; }
                else        h01pkN[(size_t)l * BH + pix] = hv16;
            }
        }
    }
}

// ---------------- final batched decoder ----------------
// out[b][t][n] = hist[t][b][:] @ Wd^T + bd. M=25600 rows (t*256+b), N=160(132), K=1024.
// grid (200, 5), block 256 (4 waves stacked on M; tile 128x32).
__global__ __launch_bounds__(256) void decode_mfma(
    const f16* __restrict__ hist,   // [100][256][1024]
    const f16* __restrict__ Wd16,   // [160][1024]
    const float* __restrict__ bd,   // [132]
    float* __restrict__ dout)       // [256][T*132]
{
    const int r0  = blockIdx.x * 128;
    const int nb0 = blockIdx.y * 32;
    const int tid  = threadIdx.x;
    const int lane = tid & 63;
    const int w    = tid >> 6;
    const int lx   = lane & 15;
    const int quad = lane >> 4;

    __shared__ __align__(16) char lds[20480];   // 2 x (A 8KB + B 2KB)

    auto stA = [&](int kt, int buf) {
        char* base = lds + buf * 10240;
#pragma unroll
        for (int i = 0; i < 2; ++i) {
            int r  = w * 32 + i * 16 + (lane >> 2);
            int sg = (lane & 3) ^ (r & 3);
            const f16* g = hist + (size_t)(r0 + r) * H_ + kt * 32 + sg * 8;
            gl_lds16(g, base + (size_t)(w * 32 + i * 16) * 64);
        }
    };
    auto stB = [&](int kt, int buf) {
        char* base = lds + 8192 + buf * 10240;
        if (w < 2) {
            int r  = w * 16 + (lane >> 2);
            int sg = (lane & 3) ^ (r & 3);
            const f16* g = Wd16 + (size_t)(nb0 + r) * H_ + kt * 32 + sg * 8;
            gl_lds16(g, base + (size_t)(w * 16) * 64);
        }
    };

    f32x4 acc[2][2];
#pragma unroll
    for (int m = 0; m < 2; ++m)
#pragma unroll
        for (int n = 0; n < 2; ++n) acc[m][n] = (f32x4){0.f, 0.f, 0.f, 0.f};

    stA(0, 0); stB(0, 0);
    for (int kt = 0; kt < 32; ++kt) {
        __syncthreads();
        if (kt + 1 < 32) { stA(kt + 1, (kt + 1) & 1); stB(kt + 1, (kt + 1) & 1); }
        const char* bA = lds + (kt & 1) * 10240;
        const char* bB = lds + 8192 + (kt & 1) * 10240;
        f16x8 af[2], bf[2];
#pragma unroll
        for (int m = 0; m < 2; ++m) {
            int R = w * 32 + m * 16 + lx;
            af[m] = *(const f16x8*)(bA + R * 64 + ((quad ^ (R & 3)) * 16));
        }
#pragma unroll
        for (int n = 0; n < 2; ++n) {
            int R = n * 16 + lx;
            bf[n] = *(const f16x8*)(bB + R * 64 + ((quad ^ (R & 3)) * 16));
        }
#pragma unroll
        for (int m = 0; m < 2; ++m)
#pragma unroll
            for (int n = 0; n < 2; ++n)
                acc[m][n] = MFMA16(af[m], bf[n], acc[m][n]);
    }

#pragma unroll
    for (int n = 0; n < 2; ++n) {
        int nn = nb0 + n * 16 + lx;
        if (nn < OUT_) {
            float bv = bd[nn];
#pragma unroll
            for (int m = 0; m < 2; ++m)
#pragma unroll
                for (int r = 0; r < 4; ++r) {
                    int row = r0 + w * 32 + m * 16 + quad * 4 + r;
                    int tt = row >> 8, b = row & 255;
                    dout[(size_t)b * (T_ * OUT_) + (size_t)tt * OUT_ + nn] = acc[m][n][r] + bv;
                }
        }
    }
}

// ---------------- host launch ----------------

extern "C" void kernel_launch(void* const* d_in, const int* in_sizes, int n_in,
                              void* d_out, int out_size, void* d_ws, size_t ws_size,
                              hipStream_t stream) {
    const float* seq  = (const float*)d_in[0];
    const float* Wih1 = (const float*)d_in[1];
    const float* Whh1 = (const float*)d_in[2];
    const float* bih1 = (const float*)d_in[3];
    const float* bhh1 = (const float*)d_in[4];
    const float* Wih2 = (const float*)d_in[5];
    const float* Whh2 = (const float*)d_in[6];
    const float* bih2 = (const float*)d_in[7];
    const float* bhh2 = (const float*)d_in[8];
    const float* Wih3 = (const float*)d_in[9];
    const float* Whh3 = (const float*)d_in[10];
    const float* bih3 = (const float*)d_in[11];
    const float* bhh3 = (const float*)d_in[12];
    const float* Wd   = (const float*)d_in[13];
    const float* bd   = (const float*)d_in[14];
    const int*   cnum = (const int*)d_in[15];
    const int*   gnum = (const int*)d_in[16];

    // ---- workspace layout
    char* p = (char*)d_ws;
    f16*  W0   = (f16*)p;  p += (size_t)4096 * 160 * 2;          // 1.31 MB
    f16*  Wd16 = (f16*)p;  p += (size_t)160 * 1024 * 2;          // 0.33 MB
    f16*  WdT  = (f16*)p;  p += (size_t)1024 * 160 * 2;          // 0.33 MB
    f16*  Wfb  = (f16*)p;  p += (size_t)4096 * 1024 * 2;         // 8.39 MB
    float* bias_comb = (float*)p; p += (size_t)3 * 4096 * 4;     // 48 KB
    float* bfb = (float*)p; p += (size_t)4096 * 4;               // 16 KB
    f16*  hist = (f16*)p;  p += (size_t)100 * BH * 2;            // 52.4 MB
    // zero region start: h01pkA + h2pkA + c_st (contiguous)
    f16*  h01pkA = (f16*)p; p += (size_t)2 * BH * 2;             // 1.05 MB
    f16*  h2pkA  = (f16*)p; p += (size_t)BH * 2;                 // 0.52 MB
    float* c_st  = (float*)p; p += (size_t)3 * BH * 4;           // 3.15 MB
    f16*  h01pkB = (f16*)p; p += (size_t)2 * BH * 2;             // 1.05 MB
    f16*  h2pkB  = (f16*)p; p += (size_t)BH * 2;                 // 0.52 MB
    f16*  Wpk   = (f16*)p; p += (size_t)6 * 64 * 32 * 2048 * 2;  // 50.3 MB
    f16*  W0pk  = (f16*)p; p += (size_t)64 * 5 * 2048 * 2;       // 1.31 MB
    f16*  seqpk = (f16*)p; p += (size_t)T_ * 5 * 256 * 32 * 2;   // 8.19 MB

    const int zero_floats = (int)(((size_t)3 * BH * 2 + (size_t)3 * BH * 4) / 4);

    // allow 120KB dynamic LDS for the step kernel (1 block/CU)
    hipFuncSetAttribute((const void*)step_mfma,
                        hipFuncAttributeMaxDynamicSharedMemorySize, 122880);

    // ---- prep
    conv_pad<<<dim3(1, 4096), 256, 0, stream>>>(Wih1, W0, 4096, IN_, 160);
    conv_pad<<<dim3(4, 160), 256, 0, stream>>>(Wd, Wd16, OUT_, H_, H_);
    convT_kernel<<<dim3(1, 1024), 256, 0, stream>>>(Wd, WdT);
    bias_add_kernel<<<16, 256, 0, stream>>>(bih1, bhh1, bias_comb + 0 * 4096, 4096);
    bias_add_kernel<<<16, 256, 0, stream>>>(bih2, bhh2, bias_comb + 1 * 4096, 4096);
    bias_add_kernel<<<16, 256, 0, stream>>>(bih3, bhh3, bias_comb + 2 * 4096, 4096);
    bfb_kernel<<<16, 256, 0, stream>>>(Wih1, bd, bfb);
    wfb_mfma<<<dim3(32, 8), 256, 0, stream>>>(W0, WdT, Wfb);
    // packed weights: wsel {0:Whh1, 1:Wih2, 2:Whh2, 3:Wih3, 4:Whh3, 5:Wfb}
    pack_w<<<dim3(64, 32), 256, 0, stream>>>(Whh1, Wpk, 0);
    pack_w<<<dim3(64, 32), 256, 0, stream>>>(Wih2, Wpk, 1);
    pack_w<<<dim3(64, 32), 256, 0, stream>>>(Whh2, Wpk, 2);
    pack_w<<<dim3(64, 32), 256, 0, stream>>>(Wih3, Wpk, 3);
    pack_w<<<dim3(64, 32), 256, 0, stream>>>(Whh3, Wpk, 4);
    pack_wf16<<<dim3(64, 32), 256, 0, stream>>>(Wfb, Wpk, 5);
    pack_w0<<<dim3(64, 5), 256, 0, stream>>>(Wih1, W0pk);
    pack_seq<<<dim3(5, T_), 256, 0, stream>>>(seq, seqpk);
    zero_kernel<<<512, 256, 0, stream>>>((float*)h01pkA, zero_floats);

    f16 *h01C = h01pkA, *h01N = h01pkB, *h2P = h2pkA, *h2N = h2pkB;
    for (int t = 0; t < T_; ++t) {
        step_mfma<<<dim3(64, 3), 512, 122880, stream>>>(
            seqpk, h2P, h01C, h01N, h2N, hist + (size_t)t * BH, c_st,
            W0pk, Wpk, bias_comb, bfb, cnum, gnum, t);
        f16* tmp;
        tmp = h01C; h01C = h01N; h01N = tmp;
        tmp = h2P;  h2P  = h2N;  h2N  = tmp;
    }

    decode_mfma<<<dim3(200, 5), 256, 0, stream>>>(hist, Wd16, bd, (float*)d_out);
}